// Round 5
// baseline (1664.324 us; speedup 1.0000x reference)
//
#include <hip/hip_runtime.h>
#include <hip/hip_fp16.h>
#include <math.h>

#define NUSERS 100000
#define NITEMS 50000
#define BATCH  64
#define CB     16                                  // batch chunk (4 chunks)
#define NCHUNK (BATCH / CB)
#define ORDER  8
#define BSHIFT 9                                   // 512 rows per bucket
#define BROWS  (1 << BSHIFT)
#define NBUCKU ((NUSERS + BROWS - 1) >> BSHIFT)    // 196
#define NBUCKI ((NITEMS + BROWS - 1) >> BSHIFT)    // 98
#define CAPU 16384
#define CAPI 24576
#define S1_BLOCKS 512
#define NREP 4

// ---------------------------------------------------------------------------
// R21: R20 (2048 scatter1 blocks) REGRESSED 44->75us: global reservation
// atomics serialize per-address (294 counters x #blocks); occupancy was never
// the limiter -> reverted to 512. SpMM theory after 4 flat micro-rounds:
// gathers are served by Infinity Cache (tauH 6.4MB / ybuf 12.8MB > 4MB
// per-XCD L2) at ~5TB/s effective -> BW wall, width/ILP-invariant (matches
// all flat results). This round: batch-chunked pipeline (4 x 16 cols; the
// recurrence is independent per batch column). Per-chunk gather targets:
// tauH-slice 1.6MB, y-slice 3.2MB -- both L2-resident per XCD. Cost: idx
// re-streamed 4x (+307MB ~ +50us). Predicted: chunk-SpMMs ~10-15us each,
// total 755 -> ~530-600. If flat -> IF-BW theory falsified, revert+pivot.
// ---------------------------------------------------------------------------

struct Coeffs { float v[ORDER + 1]; };

#define SLOTC ((size_t)(NITEMS + 1) * CB)          // halfs per tau slot (chunk)

// ---------------------------------------------------------------------------
// CSR build (R14 structure, S1_BLOCKS=512)
// ---------------------------------------------------------------------------
__global__ void init_bcur(int* __restrict__ bcurU, int* __restrict__ bcurI) {
    int t = blockIdx.x * blockDim.x + threadIdx.x;
    if (t < NBUCKU) bcurU[t] = t * CAPU;
    if (t < NBUCKI) bcurI[t] = t * CAPI;
}

__global__ void zero_pads(__half* __restrict__ tauHall, __half* __restrict__ ybuf) {
    int t = threadIdx.x;
    if (t < CB) {
        for (int k = 0; k <= ORDER; ++k)
            tauHall[(size_t)k * SLOTC + (size_t)NITEMS * CB + t] = __float2half(0.f);
        ybuf[(size_t)NUSERS * CB + t] = __float2half(0.f);
    }
}

__global__ void scatter1(const int* __restrict__ row, const int* __restrict__ col,
                         int* __restrict__ bcurU, int* __restrict__ bcurI,
                         int* __restrict__ stU, int* __restrict__ stI, int nnz) {
    __shared__ int cU[NREP][NBUCKU];
    __shared__ int cI[NREP][NBUCKI];
    const int chunk = (nnz + S1_BLOCKS - 1) / S1_BLOCKS;
    const int b0 = blockIdx.x * chunk;
    const int e0 = min(b0 + chunk, nnz);
    const int sw = threadIdx.x >> 6;
    for (int t = threadIdx.x; t < NREP * NBUCKU; t += blockDim.x) (&cU[0][0])[t] = 0;
    for (int t = threadIdx.x; t < NREP * NBUCKI; t += blockDim.x) (&cI[0][0])[t] = 0;
    __syncthreads();
    for (int i = b0 + threadIdx.x; i < e0; i += blockDim.x) {
        atomicAdd(&cU[sw][row[i] >> BSHIFT], 1);
        atomicAdd(&cI[sw][col[i] >> BSHIFT], 1);
    }
    __syncthreads();
    for (int t = threadIdx.x; t < NBUCKU; t += blockDim.x) {
        int c0 = cU[0][t], c1 = cU[1][t], c2 = cU[2][t], c3 = cU[3][t];
        int tot = c0 + c1 + c2 + c3;
        int base = (tot > 0) ? atomicAdd(&bcurU[t], tot) : 0;
        cU[0][t] = base;
        cU[1][t] = base + c0;
        cU[2][t] = base + c0 + c1;
        cU[3][t] = base + c0 + c1 + c2;
    }
    for (int t = threadIdx.x; t < NBUCKI; t += blockDim.x) {
        int c0 = cI[0][t], c1 = cI[1][t], c2 = cI[2][t], c3 = cI[3][t];
        int tot = c0 + c1 + c2 + c3;
        int base = (tot > 0) ? atomicAdd(&bcurI[t], tot) : 0;
        cI[0][t] = base;
        cI[1][t] = base + c0;
        cI[2][t] = base + c0 + c1;
        cI[3][t] = base + c0 + c1 + c2;
    }
    __syncthreads();
    for (int i = b0 + threadIdx.x; i < e0; i += blockDim.x) {
        int r = row[i], c = col[i];
        int pu = atomicAdd(&cU[sw][r >> BSHIFT], 1);
        stU[pu] = ((r & (BROWS - 1)) << 17) | c;
        int pi = atomicAdd(&cI[sw][c >> BSHIFT], 1);
        stI[pi] = ((c & (BROWS - 1)) << 17) | r;
    }
}

__global__ void scatter2(const int* __restrict__ bcur, const int* __restrict__ st,
                         int* __restrict__ ptr, int* __restrict__ degOut,
                         int* __restrict__ outIdx, int nrows, int cap, int dummyIdx) {
    __shared__ int deg[BROWS];
    __shared__ int ps[256];
    __shared__ int cur[BROWS];
    __shared__ int rs[BROWS];
    const int rbase = blockIdx.x << BSHIFT;
    const int nr = min(BROWS, nrows - rbase);
    const int lo = blockIdx.x * cap;
    const int hi = bcur[blockIdx.x];
    const int t = threadIdx.x;
    deg[2 * t] = 0;
    deg[2 * t + 1] = 0;
    __syncthreads();
    for (int j = lo + t; j < hi; j += 256)
        atomicAdd(&deg[st[j] >> 17], 1);
    __syncthreads();
    int a = deg[2 * t];
    int b = deg[2 * t + 1];
    int pa = (a + 15) & ~15;
    int pb = (b + 15) & ~15;
    ps[t] = pa + pb;
    __syncthreads();
    for (int off = 1; off < 256; off <<= 1) {
        int u = (t >= off) ? ps[t - off] : 0;
        __syncthreads();
        ps[t] += u;
        __syncthreads();
    }
    int excl = (t > 0) ? ps[t - 1] : 0;
    int p0 = lo + excl;
    int p1 = p0 + pa;
    rs[2 * t] = p0;
    rs[2 * t + 1] = p1;
    cur[2 * t] = p0;
    cur[2 * t + 1] = p1;
    if (2 * t < nr)     { ptr[rbase + 2 * t] = p0;     degOut[rbase + 2 * t] = a; }
    if (2 * t + 1 < nr) { ptr[rbase + 2 * t + 1] = p1; degOut[rbase + 2 * t + 1] = b; }
    __syncthreads();
    for (int j = lo + t; j < hi; j += 256) {
        int v = st[j];
        int p = atomicAdd(&cur[v >> 17], 1);
        outIdx[p] = v & 0x1FFFF;
    }
    __syncthreads();
    for (int i = t; i < nr; i += 256) {
        int endReal = cur[i];
        int endPad  = rs[i] + ((deg[i] + 15) & ~15);
        for (int j = endReal; j < endPad; ++j) outIdx[j] = dummyIdx;
    }
}

// ---------------------------------------------------------------------------
// per-chunk transposes (thread-per-item, coalesced along NITEMS)
// ---------------------------------------------------------------------------
__global__ void transpose_scale_cb(const float* __restrict__ in, int b0,
                                   const int* __restrict__ ideg,
                                   float* __restrict__ tauF,
                                   __half* __restrict__ tauH) {
    int c = blockIdx.x * blockDim.x + threadIdx.x;
    if (c >= NITEMS) return;
    int d = ideg[c];
    float dis = (d > 0) ? rsqrtf((float)d) : 0.0f;
    float v[CB];
    #pragma unroll
    for (int r = 0; r < CB; ++r)
        v[r] = dis * in[(size_t)(b0 + r) * NITEMS + c];
    #pragma unroll
    for (int r = 0; r < CB; r += 4)
        *(float4*)&tauF[(size_t)c * CB + r] = make_float4(v[r], v[r+1], v[r+2], v[r+3]);
    union { __half2 h2[8]; uint4 u4[2]; } pk;
    #pragma unroll
    for (int j = 0; j < 8; ++j) pk.h2[j] = __floats2half2_rn(v[2*j], v[2*j+1]);
    uint4* dst = (uint4*)&tauH[(size_t)c * CB];
    dst[0] = pk.u4[0];
    dst[1] = pk.u4[1];
}

__global__ void transpose_out_cb(const __half* __restrict__ tauHall, int b0,
                                 const float* __restrict__ signal,
                                 const int* __restrict__ ideg, float csum, Coeffs cf,
                                 float* __restrict__ out) {
    int c = blockIdx.x * blockDim.x + threadIdx.x;
    if (c >= NITEMS) return;
    float s[CB];
    #pragma unroll
    for (int r = 0; r < CB; ++r) s[r] = 0.f;
    for (int k = 0; k <= ORDER; ++k) {
        union { uint4 u4[2]; __half2 h2[8]; } pk;
        const uint4* src = (const uint4*)&tauHall[(size_t)k * SLOTC + (size_t)c * CB];
        pk.u4[0] = src[0];
        pk.u4[1] = src[1];
        float ck = cf.v[k];
        #pragma unroll
        for (int j = 0; j < 8; ++j) {
            float2 f = __half22float2(pk.h2[j]);
            s[2*j]     += ck * f.x;
            s[2*j + 1] += ck * f.y;
        }
    }
    int d = ideg[c];
    if (d > 0) {
        float sc = sqrtf((float)d);
        #pragma unroll
        for (int r = 0; r < CB; ++r)
            out[(size_t)(b0 + r) * NITEMS + c] = sc * s[r];
    } else {
        #pragma unroll
        for (int r = 0; r < CB; ++r)
            out[(size_t)(b0 + r) * NITEMS + c] = csum * signal[(size_t)(b0 + r) * NITEMS + c];
    }
}

// ---------------------------------------------------------------------------
// 4-row gather core, CB=16: rows are 8 x __half2 (32B). 8 subgroups x 8 lanes;
// each sub handles 2 nnz/iter (idx int2, 8B-aligned: row bases are 16-int
// aligned). Same iteration count as CB=64 core; half the bytes.
// ---------------------------------------------------------------------------
__device__ __forceinline__ void gather4_cb(const int* __restrict__ idx,
                                           const __half2* __restrict__ x2,
                                           const int* b, const int* n,
                                           int sub, int bh, float2* a) {
    const char* __restrict__ xb = (const char*)x2;
    const char* __restrict__ ib = (const char*)idx;
    const unsigned bhoff = (unsigned)bh << 2;
    unsigned jb[4];
    int nmax = 0;
    #pragma unroll
    for (int q = 0; q < 4; ++q) {
        jb[q] = ((unsigned)b[q] + ((unsigned)sub << 1)) << 2;   // byte offset
        nmax = max(nmax, n[q]);
    }
    for (int it = 0; it < nmax; ++it) {
        #pragma unroll
        for (int q = 0; q < 4; ++q) {
            if (it < n[q]) {
                int2 ii = *(const int2*)(ib + jb[q]);
                __half2 v0 = *(const __half2*)(xb + (((unsigned)ii.x << 5) + bhoff));
                __half2 v1 = *(const __half2*)(xb + (((unsigned)ii.y << 5) + bhoff));
                float2 f = __half22float2(__hadd2(v0, v1));
                a[q].x += f.x;
                a[q].y += f.y;
                jb[q] += 64;
            }
        }
    }
    #pragma unroll
    for (int q = 0; q < 4; ++q) {
        a[q].x += __shfl_xor(a[q].x, 8);  a[q].y += __shfl_xor(a[q].y, 8);
        a[q].x += __shfl_xor(a[q].x, 16); a[q].y += __shfl_xor(a[q].y, 16);
        a[q].x += __shfl_xor(a[q].x, 32); a[q].y += __shfl_xor(a[q].y, 32);
    }
}

// user side: y[u] = (1/deg_u) * sum tauH[col]   (chunk slice)
__global__ void spmm_user_cb(const int* __restrict__ ptr, const int* __restrict__ deg,
                             const int* __restrict__ idx,
                             const __half2* __restrict__ tauH2, __half2* __restrict__ y2) {
    const int lane = threadIdx.x & 63;
    const int w = (blockIdx.x * blockDim.x + threadIdx.x) >> 6;
    const int H = NUSERS / 4;
    if (w >= H) return;
    int r[4] = {w, w + H, w + 2 * H, w + 3 * H};
    const int sub = lane >> 3;
    const int bh  = lane & 7;
    int b[4], d[4], n[4];
    #pragma unroll
    for (int q = 0; q < 4; ++q) {
        b[q] = ptr[r[q]];
        d[q] = deg[r[q]];
        n[q] = (d[q] + 15) >> 4;
    }
    float2 a[4] = {{0,0},{0,0},{0,0},{0,0}};
    gather4_cb(idx, tauH2, b, n, sub, bh, a);
    if (lane < 8) {
        #pragma unroll
        for (int q = 0; q < 4; ++q) {
            float s = (d[q] > 0) ? 1.0f / (float)d[q] : 0.0f;
            y2[(size_t)r[q] * 8 + bh] = __floats2half2_rn(s * a[q].x, s * a[q].y);
        }
    }
}

// item, first step: tau1 = tau0 - (2/deg)*z
__global__ void spmm_item_first_cb(const int* __restrict__ ptr, const int* __restrict__ deg,
                                   const int* __restrict__ idx, const __half2* __restrict__ y2,
                                   const float* __restrict__ tau0, float* __restrict__ tau1,
                                   __half2* __restrict__ tauH1) {
    const int lane = threadIdx.x & 63;
    const int w = (blockIdx.x * blockDim.x + threadIdx.x) >> 6;
    const int H = NITEMS / 4;
    if (w >= H) return;
    int r[4] = {w, w + H, w + 2 * H, w + 3 * H};
    const int sub = lane >> 3;
    const int bh  = lane & 7;
    int b[4], d[4], n[4];
    #pragma unroll
    for (int q = 0; q < 4; ++q) {
        b[q] = ptr[r[q]];
        d[q] = deg[r[q]];
        n[q] = (d[q] + 15) >> 4;
    }
    float2 a[4] = {{0,0},{0,0},{0,0},{0,0}};
    gather4_cb(idx, y2, b, n, sub, bh, a);
    if (lane < 8) {
        #pragma unroll
        for (int q = 0; q < 4; ++q) {
            float inv = (d[q] > 0) ? 1.0f / (float)d[q] : 0.0f;
            float s2 = 2.0f * inv;
            size_t base = (size_t)r[q] * CB + (bh << 1);
            float2 t0v = *(const float2*)&tau0[base];
            float2 t;
            t.x = t0v.x - s2 * a[q].x;
            t.y = t0v.y - s2 * a[q].y;
            *(float2*)&tau1[base] = t;
            tauH1[(size_t)r[q] * 8 + bh] = __floats2half2_rn(t.x, t.y);
        }
    }
}

// item, general step: t2 = 2*t1 - (4/deg)*z - t0
__global__ void spmm_item_k_cb(const int* __restrict__ ptr, const int* __restrict__ deg,
                               const int* __restrict__ idx, const __half2* __restrict__ y2,
                               const float* __restrict__ tau1, float* __restrict__ tau0,
                               __half2* __restrict__ tauHk) {
    const int lane = threadIdx.x & 63;
    const int w = (blockIdx.x * blockDim.x + threadIdx.x) >> 6;
    const int H = NITEMS / 4;
    if (w >= H) return;
    int r[4] = {w, w + H, w + 2 * H, w + 3 * H};
    const int sub = lane >> 3;
    const int bh  = lane & 7;
    int b[4], d[4], n[4];
    #pragma unroll
    for (int q = 0; q < 4; ++q) {
        b[q] = ptr[r[q]];
        d[q] = deg[r[q]];
        n[q] = (d[q] + 15) >> 4;
    }
    float2 a[4] = {{0,0},{0,0},{0,0},{0,0}};
    gather4_cb(idx, y2, b, n, sub, bh, a);
    if (lane < 8) {
        #pragma unroll
        for (int q = 0; q < 4; ++q) {
            float inv = (d[q] > 0) ? 1.0f / (float)d[q] : 0.0f;
            float s4 = 4.0f * inv;
            size_t base = (size_t)r[q] * CB + (bh << 1);
            float2 t1v = *(const float2*)&tau1[base];
            float2 t0v = *(const float2*)&tau0[base];
            float2 t2;
            t2.x = 2.0f * t1v.x - s4 * a[q].x - t0v.x;
            t2.y = 2.0f * t1v.y - s4 * a[q].y - t0v.y;
            *(float2*)&tau0[base] = t2;
            tauHk[(size_t)r[q] * 8 + bh] = __floats2half2_rn(t2.x, t2.y);
        }
    }
}

// ---------------------------------------------------------------------------
// Host-side exact replica of reference cheby_coeffs
// ---------------------------------------------------------------------------
static void cheby_coeffs_host(float* c) {
    const int order = ORDER, flatness = 2;
    const double PI = 3.14159265358979323846;
    double tgt[ORDER + 1], nodes[ORDER + 1];
    for (int x = 0; x <= order; ++x) {
        double xv = cos((double)(order - x) / order * PI);
        xv = nearbyint(xv * 1000.0) / 1000.0;
        double t = (xv < 0.0) ? pow(-xv, (double)flatness) * 0.5 + 0.5
                              : pow(xv, (double)flatness) * (-0.5) + 0.5;
        tgt[x] = nearbyint(t * 1000.0) / 1000.0;
    }
    for (int k = 1; k <= order + 1; ++k)
        nodes[k - 1] = cos((order + 1 + 0.5 - k) / (double)(order + 1) * PI);

    double prev[ORDER + 1], cur[ORDER + 1], nxt[ORDER + 1];
    double sums[ORDER + 1];
    double s0 = 0, s1 = 0;
    for (int i = 0; i <= order; ++i) {
        prev[i] = tgt[i];
        cur[i]  = nodes[i] * tgt[i];
        s0 += prev[i];
        s1 += cur[i];
    }
    sums[0] = s0; sums[1] = s1;
    for (int j = 2; j <= order; ++j) {
        double s = 0;
        for (int i = 0; i <= order; ++i) {
            nxt[i] = nodes[i] * cur[i] * 2.0 - prev[i];
            s += nxt[i];
        }
        sums[j] = s;
        for (int i = 0; i <= order; ++i) { prev[i] = cur[i]; cur[i] = nxt[i]; }
    }
    for (int j = 0; j <= order; ++j)
        c[j] = (float)(sums[j] * (2.0 / (order + 1)));
    c[0] *= 0.5f;
}

extern "C" void kernel_launch(void* const* d_in, const int* in_sizes, int n_in,
                              void* d_out, int out_size, void* d_ws, size_t ws_size,
                              hipStream_t stream) {
    const float* signal = (const float*)d_in[0];   // [BATCH, NITEMS]
    const int*   row    = (const int*)d_in[2];     // [NNZ] -> users
    const int*   col    = (const int*)d_in[3];     // [NNZ] -> items
    const int nnz = in_sizes[1];

    char* wsb = (char*)d_ws;
    size_t off = 0;
    auto carve = [&](size_t nbytes) {
        void* p = wsb + off;
        off += (nbytes + 255) & ~(size_t)255;
        return p;
    };
    const size_t NEU = (size_t)NBUCKU * CAPU;
    const size_t NEI = (size_t)NBUCKI * CAPI;
    float*  tauFA  = (float*)carve((size_t)NITEMS * CB * 4);
    float*  tauFB  = (float*)carve((size_t)NITEMS * CB * 4);
    __half* tauH   = (__half*)carve((ORDER + 1) * SLOTC * 2);
    __half* ybuf   = (__half*)carve(((size_t)NUSERS + 1) * CB * 2);
    int*    uptr   = (int*)carve(NUSERS * 4);
    int*    iptr   = (int*)carve(NITEMS * 4);
    int*    udeg   = (int*)carve(NUSERS * 4);
    int*    ideg   = (int*)carve(NITEMS * 4);
    int*    bcurU  = (int*)carve(NBUCKU * 4);
    int*    bcurI  = (int*)carve(NBUCKI * 4);
    int*    ucol   = (int*)carve(NEU * 4);
    int*    irow   = (int*)carve(NEI * 4);
    int*    stU    = (int*)carve(NEU * 4);
    int*    stI    = (int*)carve(NEI * 4);
    (void)ws_size;

    float c[ORDER + 1];
    cheby_coeffs_host(c);
    Coeffs cf;
    float csum = 0.f;
    for (int k = 0; k <= ORDER; ++k) { cf.v[k] = c[k]; csum += c[k]; }

    // ---- CSR build ----
    init_bcur<<<1, 256, 0, stream>>>(bcurU, bcurI);
    scatter1<<<S1_BLOCKS, 256, 0, stream>>>(row, col, bcurU, bcurI, stU, stI, nnz);
    scatter2<<<NBUCKU, 256, 0, stream>>>(bcurU, stU, uptr, udeg, ucol, NUSERS, CAPU, NITEMS);
    scatter2<<<NBUCKI, 256, 0, stream>>>(bcurI, stI, iptr, ideg, irow, NITEMS, CAPI, NUSERS);
    zero_pads<<<1, 64, 0, stream>>>(tauH, ybuf);

    const int ug = (NUSERS / 4) * 64 / 256;   // 6250 blocks
    const int ig = (NITEMS / 4) * 64 / 256;   // 3125 blocks
    const int tg = (NITEMS + 255) / 256;

    for (int ch = 0; ch < NCHUNK; ++ch) {
        const int b0 = ch * CB;

        transpose_scale_cb<<<tg, 256, 0, stream>>>(signal, b0, ideg, tauFA, tauH);

        // k = 1
        spmm_user_cb<<<ug, 256, 0, stream>>>(uptr, udeg, ucol,
                                             (const __half2*)tauH, (__half2*)ybuf);
        spmm_item_first_cb<<<ig, 256, 0, stream>>>(iptr, ideg, irow,
                                                   (const __half2*)ybuf, tauFA, tauFB,
                                                   (__half2*)(tauH + SLOTC));

        float* t0 = tauFA;
        float* t1 = tauFB;
        for (int k = 2; k <= ORDER; ++k) {
            spmm_user_cb<<<ug, 256, 0, stream>>>(uptr, udeg, ucol,
                                                 (const __half2*)(tauH + (size_t)(k - 1) * SLOTC),
                                                 (__half2*)ybuf);
            spmm_item_k_cb<<<ig, 256, 0, stream>>>(iptr, ideg, irow,
                                                   (const __half2*)ybuf, t1, t0,
                                                   (__half2*)(tauH + (size_t)k * SLOTC));
            float* tmp = t0; t0 = t1; t1 = tmp;
        }

        transpose_out_cb<<<tg, 256, 0, stream>>>(tauH, b0, signal, ideg, csum, cf,
                                                 (float*)d_out);
    }
}